// Round 3
// baseline (675.717 us; speedup 1.0000x reference)
//
#include <hip/hip_runtime.h>
#include <hip/hip_bf16.h>
#include <hip/hip_fp16.h>

typedef __attribute__((ext_vector_type(8))) short short8;
typedef __attribute__((ext_vector_type(4))) float f32x4;
typedef __attribute__((ext_vector_type(4))) unsigned short us4;

#define MFMA16(a, b, c) __builtin_amdgcn_mfma_f32_16x16x32_bf16(a, b, c, 0, 0, 0)

__device__ __forceinline__ short f2bf(float f) {
    unsigned u = __float_as_uint(f);
    unsigned r = (u + 0x7fffu + ((u >> 16) & 1u)) >> 16;
    return (short)r;
}
__device__ __forceinline__ float h2f(unsigned short u) {
    __half_raw r; r.x = u;
    return __half2float(__half(r));
}

// ---------------- prep kernels ----------------

__global__ __launch_bounds__(256) void k_wcvt(const float* qkv_w, const float* proj_w,
                                              const float* lsc, short* wq, short* wp,
                                              float* scales) {
    int i = blockIdx.x * 256 + threadIdx.x;
    if (i < 576 * 192) wq[i] = f2bf(qkv_w[i]);
    else {
        int j = i - 576 * 192;
        if (j < 192 * 192) wp[j] = f2bf(proj_w[j]);
    }
    if (blockIdx.x == 0 && threadIdx.x < 6)
        scales[threadIdx.x] = expf(fminf(lsc[threadIdx.x], 4.60517018598809136f));
}

// cpb MLP: 507 entries, 3 -> 512 relu -> 6
__global__ __launch_bounds__(64) void k_tbl(const float* tab, const float* w1, const float* b1,
                                            const float* w2, float* tbl) {
    int e = blockIdx.x;
    int t = threadIdx.x;
    float c0 = tab[e * 3 + 0], c1 = tab[e * 3 + 1], c2 = tab[e * 3 + 2];
    float acc[6] = {0.f, 0.f, 0.f, 0.f, 0.f, 0.f};
    for (int u = t; u < 512; u += 64) {
        float hv = c0 * w1[u * 3 + 0] + c1 * w1[u * 3 + 1] + c2 * w1[u * 3 + 2] + b1[u];
        hv = fmaxf(hv, 0.f);
        #pragma unroll
        for (int hh = 0; hh < 6; ++hh) acc[hh] += hv * w2[hh * 512 + u];
    }
    #pragma unroll
    for (int hh = 0; hh < 6; ++hh) {
        float v = acc[hh];
        for (int off = 32; off > 0; off >>= 1) v += __shfl_xor(v, off, 64);
        if (t == 0) tbl[e * 6 + hh] = v;
    }
}

// cpb_t[h][q][k112] = 16*sigmoid(tbl[rpi[q*98+k]][h]) (fp16), 0 for k>=98
__global__ __launch_bounds__(128) void k_cpb(const float* tbl, const int* rpi, __half* cpb_t) {
    int k = threadIdx.x;
    if (k >= 112) return;
    int q = blockIdx.x % 98, h = blockIdx.x / 98;
    float v = 0.f;
    if (k < 98) {
        float t = tbl[rpi[q * 98 + k] * 6 + h];
        v = 16.f / (1.f + expf(-t));
    }
    cpb_t[(h * 98 + q) * 112 + k] = __float2half(v);
}

// mpad[w][q][k112] = mask[w][q][k], -60000 for k>=98
__global__ __launch_bounds__(128) void k_mpad(const float* mask, float* mpad) {
    int k = threadIdx.x;
    if (k >= 112) return;
    int q = blockIdx.x % 98, w = blockIdx.x / 98;
    float v = (k < 98) ? mask[(w * 98 + q) * 98 + k] : -60000.f;
    mpad[(w * 98 + q) * 112 + k] = v;
}

// ---------------- qkv GEMM: register-resident, no LDS, no barriers ----------------
// block = 64 rows; wave wv: rows wr..wr+32, cols (wv&1)*32 within each 64-col tile.
__global__ __launch_bounds__(256) void k_qkv(const float* x, const short* wq, const float* qkv_b,
                                             const float* scales, short* qkvo) {
    int tid = threadIdx.x;
    int mtile = blockIdx.x;
    int lane = tid & 63, wv = tid >> 6;
    int l16 = lane & 15, q4 = lane >> 4;
    int wr = (wv >> 1) * 32;
    int wc32 = (wv & 1) * 32;

    #pragma unroll 1
    for (int mf = 0; mf < 2; ++mf) {
        // A fragments: 16 rows (lane=l16) x K=192, fp32 -> bf16 in-register
        int arow = mtile * 64 + wr + mf * 16 + l16;
        const float* xp = x + (size_t)arow * 192 + q4 * 8;
        short8 af[6];
        #pragma unroll
        for (int ks = 0; ks < 6; ++ks) {
            float4 f0 = *(const float4*)(xp + ks * 32);
            float4 f1 = *(const float4*)(xp + ks * 32 + 4);
            union { int i4[4]; short8 s; } u;
            asm("v_cvt_pk_bf16_f32 %0, %1, %2" : "=v"(u.i4[0]) : "v"(f0.x), "v"(f0.y));
            asm("v_cvt_pk_bf16_f32 %0, %1, %2" : "=v"(u.i4[1]) : "v"(f0.z), "v"(f0.w));
            asm("v_cvt_pk_bf16_f32 %0, %1, %2" : "=v"(u.i4[2]) : "v"(f1.x), "v"(f1.y));
            asm("v_cvt_pk_bf16_f32 %0, %1, %2" : "=v"(u.i4[3]) : "v"(f1.z), "v"(f1.w));
            af[ks] = u.s;
        }
        // output row offsets (C rows = q4*4+i)
        int rowoff[4];
        #pragma unroll
        for (int i = 0; i < 4; ++i) {
            int m = mtile * 64 + wr + mf * 16 + q4 * 4 + i;
            int bb = m / 98;
            rowoff[i] = bb * 56448 + (m - bb * 98) * 32;
        }
        #pragma unroll 1
        for (int nt = 0; nt < 9; ++nt) {
            int c0 = nt * 64 + wc32 + l16;
            const short* bp = wq + (size_t)c0 * 192 + q4 * 8;
            f32x4 acc0 = {0.f, 0.f, 0.f, 0.f}, acc1 = {0.f, 0.f, 0.f, 0.f};
            #pragma unroll
            for (int ks = 0; ks < 6; ++ks) {
                short8 b0 = *(const short8*)(bp + ks * 32);
                short8 b1 = *(const short8*)(bp + 16 * 192 + ks * 32);
                acc0 = MFMA16(af[ks], b0, acc0);
                acc1 = MFMA16(af[ks], b1, acc1);
            }
            int hw = nt * 2 + (wv & 1);      // head-dim group 0..17
            int which = hw / 6;              // 0=q 1=k 2=v
            int hhq = hw - which * 6;
            float sc = (which == 0) ? scales[hhq] : 1.f;
            int colbase = hw * 3136 + l16;   // (which*6+hh)*3136 + d
            float bia0 = qkv_b[c0];
            float bia1 = qkv_b[c0 + 16];
            #pragma unroll
            for (int i = 0; i < 4; ++i) {
                float v0 = acc0[i] + bia0;
                float v1 = acc1[i] + bia1;
                if (which < 2) {
                    float ss = v0 * v0 + v1 * v1;
                    ss += __shfl_xor(ss, 1, 16);
                    ss += __shfl_xor(ss, 2, 16);
                    ss += __shfl_xor(ss, 4, 16);
                    ss += __shfl_xor(ss, 8, 16);
                    float rn = sc / fmaxf(sqrtf(ss), 1e-12f);
                    v0 *= rn; v1 *= rn;
                }
                qkvo[rowoff[i] + colbase]      = f2bf(v0);
                qkvo[rowoff[i] + colbase + 16] = f2bf(v1);
            }
        }
    }
}

// ---------------- fused attention: no LDS, no barriers ----------------
__global__ __launch_bounds__(448) void k_attn(const short* qkv, const __half* cpb_t,
                                              const float* mpad, short* tmp) {
    int tid = threadIdx.x;
    int wv = tid >> 6;
    int lane = tid & 63;
    int l16 = lane & 15, q4 = lane >> 4;
    int bx = blockIdx.x;          // ((w*6+hh)*8 + gb)
    int gb = bx & 7;
    int wh = bx >> 3;
    int hh = wh % 6, w = wh / 6;

    int q = wv * 16 + l16;
    int qc = q < 98 ? q : 97;
    float bias[7][4];
    #pragma unroll
    for (int ct = 0; ct < 7; ++ct) {
        int k0 = ct * 16 + q4 * 4;
        us4 ch = *(const us4*)(cpb_t + (hh * 98 + qc) * 112 + k0);
        float4 mk = *(const float4*)(mpad + (w * 98 + qc) * 112 + k0);
        bias[ct][0] = h2f(ch.x) + mk.x;
        bias[ct][1] = h2f(ch.y) + mk.y;
        bias[ct][2] = h2f(ch.z) + mk.z;
        bias[ct][3] = h2f(ch.w) + mk.w;
    }

    int srcA = ((q4 & 1) * 2) * 16 + l16;
    int srcB = srcA + 16;
    bool hi = (q4 & 2) != 0;

    #pragma unroll 1
    for (int g = 0; g < 4; ++g) {
        int b = (gb * 4 + g) * 64 + w;
        const short* Qp = qkv + ((size_t)b * 18 + hh) * 3136;
        const short* Kp = Qp + 6 * 3136;
        const short* Vp = Qp + 12 * 3136;

        short8 qf = *(const short8*)(Qp + (wv * 16 + l16) * 32 + q4 * 8);
        f32x4 zz = {0.f, 0.f, 0.f, 0.f};
        f32x4 cc[7];
        #pragma unroll
        for (int ct = 0; ct < 7; ++ct) {
            short8 kf = *(const short8*)(Kp + (ct * 16 + l16) * 32 + q4 * 8);
            cc[ct] = MFMA16(kf, qf, zz);
        }
        float mx = -1e30f;
        #pragma unroll
        for (int ct = 0; ct < 7; ++ct)
            #pragma unroll
            for (int i = 0; i < 4; ++i) {
                float s = cc[ct][i] + bias[ct][i];
                cc[ct][i] = s;
                mx = fmaxf(mx, s);
            }
        mx = fmaxf(mx, __shfl_xor(mx, 16, 64));
        mx = fmaxf(mx, __shfl_xor(mx, 32, 64));
        float sm = 0.f;
        #pragma unroll
        for (int ct = 0; ct < 7; ++ct)
            #pragma unroll
            for (int i = 0; i < 4; ++i) {
                float e = __expf(cc[ct][i] - mx);
                cc[ct][i] = e;
                sm += e;
            }
        sm += __shfl_xor(sm, 16, 64);
        sm += __shfl_xor(sm, 32, 64);
        float ri = 1.f / sm;
        int W[7][2];
        #pragma unroll
        for (int ct = 0; ct < 7; ++ct) {
            float a0 = cc[ct][0] * ri, a1 = cc[ct][1] * ri;
            float a2 = cc[ct][2] * ri, a3 = cc[ct][3] * ri;
            asm("v_cvt_pk_bf16_f32 %0, %1, %2" : "=v"(W[ct][0]) : "v"(a0), "v"(a1));
            asm("v_cvt_pk_bf16_f32 %0, %1, %2" : "=v"(W[ct][1]) : "v"(a2), "v"(a3));
        }
        f32x4 o0 = zz, o1 = zz;
        #pragma unroll
        for (int km = 0; km < 4; ++km) {
            int A0 = __shfl(W[2 * km][0], srcA, 64), B0 = __shfl(W[2 * km + 1][0], srcA, 64);
            int A1 = __shfl(W[2 * km][1], srcA, 64), B1 = __shfl(W[2 * km + 1][1], srcA, 64);
            int A2 = __shfl(W[2 * km][0], srcB, 64), B2 = __shfl(W[2 * km + 1][0], srcB, 64);
            int A3 = __shfl(W[2 * km][1], srcB, 64), B3 = __shfl(W[2 * km + 1][1], srcB, 64);
            int w0 = hi ? B0 : A0, w1 = hi ? B1 : A1;
            int w2 = hi ? B2 : A2, w3 = hi ? B3 : A3;
            if (km == 3 && q4 >= 2) { w0 = 0; w1 = 0; w2 = 0; w3 = 0; }
            union { int i4[4]; short8 s; } ua;
            ua.i4[0] = w0; ua.i4[1] = w1; ua.i4[2] = w2; ua.i4[3] = w3;
            short8 bv0, bv1;
            #pragma unroll
            for (int j = 0; j < 8; ++j) {
                int r = km * 32 + q4 * 8 + j;
                int rr = (r < 98) ? r : 0;
                int rb = rr * 32 + l16;
                bv0[j] = Vp[rb];
                bv1[j] = Vp[rb + 16];
            }
            o0 = MFMA16(ua.s, bv0, o0);
            o1 = MFMA16(ua.s, bv1, o1);
        }
        #pragma unroll
        for (int i = 0; i < 4; ++i) {
            int qo = wv * 16 + q4 * 4 + i;
            if (qo < 98) {
                size_t ob = ((size_t)b * 98 + qo) * 192 + hh * 32;
                tmp[ob + l16]      = f2bf(o0[i]);
                tmp[ob + 16 + l16] = f2bf(o1[i]);
            }
        }
    }
}

// ---------------- proj GEMM: register-resident, no LDS, no barriers ----------------
__global__ __launch_bounds__(256) void k_proj(const short* tmp, const short* wp,
                                              const float* proj_b, float* outp) {
    int tid = threadIdx.x, mtile = blockIdx.x;
    int lane = tid & 63, wv = tid >> 6;
    int l16 = lane & 15, q4 = lane >> 4;
    int wr = (wv >> 1) * 32;
    int wc32 = (wv & 1) * 32;
    #pragma unroll 1
    for (int mf = 0; mf < 2; ++mf) {
        int arow = mtile * 64 + wr + mf * 16 + l16;
        const short* ap = tmp + (size_t)arow * 192 + q4 * 8;
        short8 af[6];
        #pragma unroll
        for (int ks = 0; ks < 6; ++ks) af[ks] = *(const short8*)(ap + ks * 32);
        int mrow0 = mtile * 64 + wr + mf * 16 + q4 * 4;
        #pragma unroll 1
        for (int nt = 0; nt < 3; ++nt) {
            int c0 = nt * 64 + wc32 + l16;
            const short* bp = wp + (size_t)c0 * 192 + q4 * 8;
            f32x4 acc0 = {0.f, 0.f, 0.f, 0.f}, acc1 = {0.f, 0.f, 0.f, 0.f};
            #pragma unroll
            for (int ks = 0; ks < 6; ++ks) {
                short8 b0 = *(const short8*)(bp + ks * 32);
                short8 b1 = *(const short8*)(bp + 16 * 192 + ks * 32);
                acc0 = MFMA16(af[ks], b0, acc0);
                acc1 = MFMA16(af[ks], b1, acc1);
            }
            float bia0 = proj_b[c0];
            float bia1 = proj_b[c0 + 16];
            #pragma unroll
            for (int i = 0; i < 4; ++i) {
                size_t ob = (size_t)(mrow0 + i) * 192;
                outp[ob + c0]      = acc0[i] + bia0;
                outp[ob + c0 + 16] = acc1[i] + bia1;
            }
        }
    }
}

extern "C" void kernel_launch(void* const* d_in, const int* in_sizes, int n_in,
                              void* d_out, int out_size, void* d_ws, size_t ws_size,
                              hipStream_t stream) {
    const float* x    = (const float*)d_in[0];
    const float* mask = (const float*)d_in[1];
    const float* qkvw = (const float*)d_in[2];
    const float* qkvb = (const float*)d_in[3];
    const float* lsc  = (const float*)d_in[4];
    const float* w1   = (const float*)d_in[5];
    const float* b1   = (const float*)d_in[6];
    const float* w2   = (const float*)d_in[7];
    const float* pw   = (const float*)d_in[8];
    const float* pb   = (const float*)d_in[9];
    const float* tab  = (const float*)d_in[10];
    const int*   rpi  = (const int*)d_in[11];

    char* ws = (char*)d_ws;
    short*  qkvo   = (short*)(ws + 0);               // 231,211,008
    short*  tmp    = (short*)(ws + 231211008LL);     //  77,070,336
    short*  wq     = (short*)(ws + 308281344LL);     //     221,184
    short*  wp     = (short*)(ws + 308502528LL);     //      73,728
    float*  tbl    = (float*)(ws + 308576256LL);     //      12,288
    float*  scales = (float*)(ws + 308588544LL);     //         256
    __half* cpb_t  = (__half*)(ws + 308588800LL);    //     135,168
    float*  mpad   = (float*)(ws + 308723968LL);     //   2,809,856
    float*  outp   = (float*)d_out;

    k_wcvt<<<576, 256, 0, stream>>>(qkvw, pw, lsc, wq, wp, scales);
    k_tbl<<<507, 64, 0, stream>>>(tab, w1, b1, w2, tbl);
    k_cpb<<<588, 128, 0, stream>>>(tbl, rpi, cpb_t);
    k_mpad<<<6272, 128, 0, stream>>>(mask, mpad);
    k_qkv<<<3136, 256, 0, stream>>>(x, wq, qkvb, scales, qkvo);
    k_attn<<<3072, 448, 0, stream>>>(qkvo, cpb_t, mpad, tmp);
    k_proj<<<3136, 256, 0, stream>>>(tmp, wp, pb, outp);
}

// Round 4
// 433.075 us; speedup vs baseline: 1.5603x; 1.5603x over previous
//
#include <hip/hip_runtime.h>
#include <hip/hip_bf16.h>
#include <hip/hip_fp16.h>

typedef __attribute__((ext_vector_type(8))) short short8;
typedef __attribute__((ext_vector_type(4))) float f32x4;
typedef __attribute__((ext_vector_type(4))) unsigned short us4;

#define MFMA16(a, b, c) __builtin_amdgcn_mfma_f32_16x16x32_bf16(a, b, c, 0, 0, 0)
#define LN100 4.605170185988091f

__device__ __forceinline__ short f2bf(float f) {
    unsigned u = __float_as_uint(f);
    unsigned r = (u + 0x7fffu + ((u >> 16) & 1u)) >> 16;
    return (short)r;
}
__device__ __forceinline__ float h2f(unsigned short u) {
    __half_raw r; r.x = u;
    return __half2float(__half(r));
}

// ---------------- prep kernels ----------------

__global__ __launch_bounds__(256) void k_wcvt(const float* qkv_w, const float* proj_w,
                                              short* wq, short* wp) {
    int i = blockIdx.x * 256 + threadIdx.x;
    if (i < 576 * 192) wq[i] = f2bf(qkv_w[i]);
    else {
        int j = i - 576 * 192;
        if (j < 192 * 192) wp[j] = f2bf(proj_w[j]);
    }
}

// cpb MLP: 507 entries, 3 -> 512 relu -> 6
__global__ __launch_bounds__(64) void k_tbl(const float* tab, const float* w1, const float* b1,
                                            const float* w2, float* tbl) {
    int e = blockIdx.x;
    int t = threadIdx.x;
    float c0 = tab[e * 3 + 0], c1 = tab[e * 3 + 1], c2 = tab[e * 3 + 2];
    float acc[6] = {0.f, 0.f, 0.f, 0.f, 0.f, 0.f};
    for (int u = t; u < 512; u += 64) {
        float hv = c0 * w1[u * 3 + 0] + c1 * w1[u * 3 + 1] + c2 * w1[u * 3 + 2] + b1[u];
        hv = fmaxf(hv, 0.f);
        #pragma unroll
        for (int hh = 0; hh < 6; ++hh) acc[hh] += hv * w2[hh * 512 + u];
    }
    #pragma unroll
    for (int hh = 0; hh < 6; ++hh) {
        float v = acc[hh];
        for (int off = 32; off > 0; off >>= 1) v += __shfl_xor(v, off, 64);
        if (t == 0) tbl[e * 6 + hh] = v;
    }
}

// bm[w][h][q][k112] = 16*sigmoid(cpb) + mask (fp16), -60000 for k>=98
__global__ __launch_bounds__(256) void k_bm(const float* tbl, const int* rpi, const float* mask,
                                            __half* bm) {
    int i = blockIdx.x * 256 + threadIdx.x;
    if (i >= 64 * 6 * 98 * 112) return;
    int k = i % 112;
    int q = (i / 112) % 98;
    int h = (i / (112 * 98)) % 6;
    int w = i / (112 * 98 * 6);
    float v;
    if (k < 98) {
        float t = tbl[rpi[q * 98 + k] * 6 + h];
        v = 16.f / (1.f + expf(-t)) + mask[(w * 98 + q) * 98 + k];
    } else v = -60000.f;
    bm[i] = __float2half(v);
}

// ---------------- fully fused kernel: one block per window ----------------
// LDS (shorts): Qs[112][192]@0, Ks[112][192]@21504, VT 6x[32][128]@43008 (ao
// overlay 6x[112][32]), Bs[64][192]@67584.  XOR chunk swizzle: chunk^=(row&7).
__global__ __launch_bounds__(448) void k_fused(const float* x, const short* wq, const float* qkv_b,
                                               const float* lsc, const short* wp, const float* proj_b,
                                               const __half* bm, float* outp) {
    __shared__ short lds[79872];
    short* Qs = lds;
    short* Ks = lds + 21504;
    short* VT = lds + 43008;
    short* Bs = lds + 67584;

    const int tid = threadIdx.x;
    const int wv = tid >> 6;
    const int lane = tid & 63;
    const int l16 = lane & 15, q4 = lane >> 4;
    const int b = blockIdx.x;
    const int w = b & 63;
    const f32x4 zz = {0.f, 0.f, 0.f, 0.f};

    // zero VT (incl. token pad 98..127)
    {
        short8 z = {0, 0, 0, 0, 0, 0, 0, 0};
        #pragma unroll
        for (int it = 0; it < 7; ++it) {
            int c = tid + it * 448;
            if (c < 3072) *(short8*)&VT[c * 8] = z;
        }
    }
    // x A-frags: 16 rows per wave, K=192, fp32->bf16 in-register
    short8 af[6];
    {
        int arow = wv * 16 + l16; if (arow > 97) arow = 97;
        const float* xp = x + ((size_t)b * 98 + arow) * 192 + q4 * 8;
        #pragma unroll
        for (int ks = 0; ks < 6; ++ks) {
            float4 f0 = *(const float4*)(xp + ks * 32);
            float4 f1 = *(const float4*)(xp + ks * 32 + 4);
            union { int i4[4]; short8 s; } u;
            asm("v_cvt_pk_bf16_f32 %0, %1, %2" : "=v"(u.i4[0]) : "v"(f0.x), "v"(f0.y));
            asm("v_cvt_pk_bf16_f32 %0, %1, %2" : "=v"(u.i4[1]) : "v"(f0.z), "v"(f0.w));
            asm("v_cvt_pk_bf16_f32 %0, %1, %2" : "=v"(u.i4[2]) : "v"(f1.x), "v"(f1.y));
            asm("v_cvt_pk_bf16_f32 %0, %1, %2" : "=v"(u.i4[3]) : "v"(f1.z), "v"(f1.w));
            af[ks] = u.s;
        }
    }
    // prologue: stage B tile 0
    short8 s0, s1, s2, s3;
    {
        int c0 = tid, c1 = tid + 448, c2 = tid + 896, c3 = tid + 1344;
        s0 = *(const short8*)(wq + (c0 / 24) * 192 + (c0 % 24) * 8);
        s1 = *(const short8*)(wq + (c1 / 24) * 192 + (c1 % 24) * 8);
        s2 = *(const short8*)(wq + (c2 / 24) * 192 + (c2 % 24) * 8);
        if (c3 < 1536) s3 = *(const short8*)(wq + (c3 / 24) * 192 + (c3 % 24) * 8);
    }
    __syncthreads();   // VT zeros visible before any VT write
    {
        int c0 = tid, c1 = tid + 448, c2 = tid + 896, c3 = tid + 1344;
        *(short8*)&Bs[(c0 / 24) * 192 + (((c0 % 24) ^ ((c0 / 24) & 7)) << 3)] = s0;
        *(short8*)&Bs[(c1 / 24) * 192 + (((c1 % 24) ^ ((c1 / 24) & 7)) << 3)] = s1;
        *(short8*)&Bs[(c2 / 24) * 192 + (((c2 % 24) ^ ((c2 / 24) & 7)) << 3)] = s2;
        if (c3 < 1536) *(short8*)&Bs[(c3 / 24) * 192 + (((c3 % 24) ^ ((c3 / 24) & 7)) << 3)] = s3;
    }
    __syncthreads();

    const int row_w = wv * 16 + q4 * 4;
    // ---- qkv GEMM: 9 col-tiles of 64 ----
    #pragma unroll 1
    for (int nt = 0; nt < 9; ++nt) {
        if (nt < 8) {   // T14: issue next tile's loads before compute
            const short* wn = wq + (nt + 1) * 64 * 192;
            int c0 = tid, c1 = tid + 448, c2 = tid + 896, c3 = tid + 1344;
            s0 = *(const short8*)(wn + (c0 / 24) * 192 + (c0 % 24) * 8);
            s1 = *(const short8*)(wn + (c1 / 24) * 192 + (c1 % 24) * 8);
            s2 = *(const short8*)(wn + (c2 / 24) * 192 + (c2 % 24) * 8);
            if (c3 < 1536) s3 = *(const short8*)(wn + (c3 / 24) * 192 + (c3 % 24) * 8);
        }
        f32x4 acc[4] = {zz, zz, zz, zz};
        #pragma unroll
        for (int ks = 0; ks < 6; ++ks)
            #pragma unroll
            for (int cf = 0; cf < 4; ++cf) {
                short8 bf = *(const short8*)&Bs[(cf * 16 + l16) * 192 +
                                                (((ks * 4 + q4) ^ (l16 & 7)) << 3)];
                acc[cf] = MFMA16(af[ks], bf, acc[cf]);
            }
        #pragma unroll
        for (int p = 0; p < 2; ++p) {
            int slot = nt * 2 + p;
            int which = slot / 6;
            int h = slot - which * 6;
            float bia0 = qkv_b[slot * 32 + l16];
            float bia1 = qkv_b[slot * 32 + 16 + l16];
            float sc = 1.0f;
            if (which == 0) sc = __expf(fminf(lsc[h], LN100));
            #pragma unroll
            for (int i = 0; i < 4; ++i) {
                float v0 = acc[2 * p][i] + bia0;
                float v1 = acc[2 * p + 1][i] + bia1;
                if (which < 2) {
                    float ss = v0 * v0 + v1 * v1;
                    ss += __shfl_xor(ss, 1, 16);
                    ss += __shfl_xor(ss, 2, 16);
                    ss += __shfl_xor(ss, 4, 16);
                    ss += __shfl_xor(ss, 8, 16);
                    float rn = sc / fmaxf(sqrtf(ss), 1e-12f);
                    v0 *= rn; v1 *= rn;
                }
                int row = row_w + i;
                if (which == 2) {
                    int swz = (((row >> 3) ^ (l16 & 7)) << 3) + (row & 7);
                    VT[h * 4096 + l16 * 128 + swz]        = f2bf(v0);
                    VT[h * 4096 + (l16 + 16) * 128 + swz] = f2bf(v1);
                } else {
                    short* T = (which == 0) ? Qs : Ks;
                    int c0i = h * 32 + l16, c1i = c0i + 16;
                    T[row * 192 + (((c0i >> 3) ^ (row & 7)) << 3) + (c0i & 7)] = f2bf(v0);
                    T[row * 192 + (((c1i >> 3) ^ (row & 7)) << 3) + (c1i & 7)] = f2bf(v1);
                }
            }
        }
        __syncthreads();
        if (nt < 8) {
            int c0 = tid, c1 = tid + 448, c2 = tid + 896, c3 = tid + 1344;
            *(short8*)&Bs[(c0 / 24) * 192 + (((c0 % 24) ^ ((c0 / 24) & 7)) << 3)] = s0;
            *(short8*)&Bs[(c1 / 24) * 192 + (((c1 % 24) ^ ((c1 / 24) & 7)) << 3)] = s1;
            *(short8*)&Bs[(c2 / 24) * 192 + (((c2 % 24) ^ ((c2 / 24) & 7)) << 3)] = s2;
            if (c3 < 1536) *(short8*)&Bs[(c3 / 24) * 192 + (((c3 % 24) ^ ((c3 / 24) & 7)) << 3)] = s3;
            __syncthreads();
        }
    }

    // ---- attention: 6 heads ----
    const int rq = wv * 16 + l16;
    const int qc = rq < 98 ? rq : 97;
    const int srcA = ((q4 & 1) * 2) * 16 + l16;
    const int srcB = srcA + 16;
    const bool hi = (q4 & 2) != 0;

    #pragma unroll 1
    for (int h = 0; h < 6; ++h) {
        const __half* bmp = bm + (((size_t)w * 6 + h) * 98 + qc) * 112;
        us4 bh[7];
        #pragma unroll
        for (int ct = 0; ct < 7; ++ct) bh[ct] = *(const us4*)(bmp + ct * 16 + q4 * 4);
        short8 qf = *(const short8*)&Qs[rq * 192 + (((h * 4 + q4) ^ (l16 & 7)) << 3)];
        f32x4 cc[7];
        #pragma unroll
        for (int ct = 0; ct < 7; ++ct) {
            int rk = ct * 16 + l16;
            short8 kf = *(const short8*)&Ks[rk * 192 + (((h * 4 + q4) ^ (l16 & 7)) << 3)];
            cc[ct] = MFMA16(kf, qf, zz);
        }
        float mx = -1e30f;
        #pragma unroll
        for (int ct = 0; ct < 7; ++ct)
            #pragma unroll
            for (int i = 0; i < 4; ++i) {
                float s = cc[ct][i] + h2f(bh[ct][i]);
                cc[ct][i] = s;
                mx = fmaxf(mx, s);
            }
        mx = fmaxf(mx, __shfl_xor(mx, 16, 64));
        mx = fmaxf(mx, __shfl_xor(mx, 32, 64));
        float sm = 0.f;
        #pragma unroll
        for (int ct = 0; ct < 7; ++ct)
            #pragma unroll
            for (int i = 0; i < 4; ++i) {
                float e = __expf(cc[ct][i] - mx);
                cc[ct][i] = e;
                sm += e;
            }
        sm += __shfl_xor(sm, 16, 64);
        sm += __shfl_xor(sm, 32, 64);
        float ri = 1.f / sm;
        int W[8][2];
        W[7][0] = 0; W[7][1] = 0;
        #pragma unroll
        for (int ct = 0; ct < 7; ++ct) {
            float a0 = cc[ct][0] * ri, a1 = cc[ct][1] * ri;
            float a2 = cc[ct][2] * ri, a3 = cc[ct][3] * ri;
            asm("v_cvt_pk_bf16_f32 %0, %1, %2" : "=v"(W[ct][0]) : "v"(a0), "v"(a1));
            asm("v_cvt_pk_bf16_f32 %0, %1, %2" : "=v"(W[ct][1]) : "v"(a2), "v"(a3));
        }
        f32x4 o0 = zz, o1 = zz;
        #pragma unroll
        for (int km = 0; km < 4; ++km) {
            int A0 = __shfl(W[2 * km][0], srcA, 64), B0 = __shfl(W[2 * km + 1][0], srcA, 64);
            int A1 = __shfl(W[2 * km][1], srcA, 64), B1 = __shfl(W[2 * km + 1][1], srcA, 64);
            int A2 = __shfl(W[2 * km][0], srcB, 64), B2 = __shfl(W[2 * km + 1][0], srcB, 64);
            int A3 = __shfl(W[2 * km][1], srcB, 64), B3 = __shfl(W[2 * km + 1][1], srcB, 64);
            union { int i4[4]; short8 s; } ua;
            ua.i4[0] = hi ? B0 : A0;
            ua.i4[1] = hi ? B1 : A1;
            ua.i4[2] = hi ? B2 : A2;
            ua.i4[3] = hi ? B3 : A3;
            int sA = h * 4096 + l16 * 128 + (((km * 4 + q4) ^ (l16 & 7)) << 3);
            short8 bv0 = *(const short8*)&VT[sA];
            short8 bv1 = *(const short8*)&VT[sA + 2048];
            o0 = MFMA16(ua.s, bv0, o0);
            o1 = MFMA16(ua.s, bv1, o1);
        }
        __syncthreads();   // all PV_h reads of VT[h] done before ao overlay
        #pragma unroll
        for (int i = 0; i < 4; ++i) {
            int q = row_w + i;
            VT[h * 4096 + q * 32 + l16]      = f2bf(o0[i]);
            VT[h * 4096 + q * 32 + 16 + l16] = f2bf(o1[i]);
        }
    }

    // ---- proj: stage pw into Qs/Ks region, A-frags from ao overlay ----
    {
        short8 pwst[11];
        #pragma unroll
        for (int it = 0; it < 11; ++it) {
            int c = tid + it * 448;
            if (c < 4608) pwst[it] = *(const short8*)(wp + (c / 24) * 192 + (c % 24) * 8);
        }
        #pragma unroll
        for (int it = 0; it < 11; ++it) {
            int c = tid + it * 448;
            if (c < 4608)
                *(short8*)&lds[(c / 24) * 192 + (((c % 24) ^ ((c / 24) & 7)) << 3)] = pwst[it];
        }
    }
    __syncthreads();
    {
        short8 pa[6];
        #pragma unroll
        for (int ks = 0; ks < 6; ++ks)
            pa[ks] = *(const short8*)&VT[ks * 4096 + rq * 32 + q4 * 8];
        f32x4 pacc[12] = {zz, zz, zz, zz, zz, zz, zz, zz, zz, zz, zz, zz};
        #pragma unroll
        for (int ks = 0; ks < 6; ++ks)
            #pragma unroll
            for (int cf = 0; cf < 12; ++cf) {
                short8 bf = *(const short8*)&lds[(cf * 16 + l16) * 192 +
                                                 (((ks * 4 + q4) ^ (l16 & 7)) << 3)];
                pacc[cf] = MFMA16(pa[ks], bf, pacc[cf]);
            }
        #pragma unroll
        for (int cf = 0; cf < 12; ++cf) {
            float bia = proj_b[cf * 16 + l16];
            #pragma unroll
            for (int i = 0; i < 4; ++i) {
                int q = row_w + i;
                if (q < 98)
                    outp[((size_t)b * 98 + q) * 192 + cf * 16 + l16] = pacc[cf][i] + bia;
            }
        }
    }
}

extern "C" void kernel_launch(void* const* d_in, const int* in_sizes, int n_in,
                              void* d_out, int out_size, void* d_ws, size_t ws_size,
                              hipStream_t stream) {
    const float* x    = (const float*)d_in[0];
    const float* mask = (const float*)d_in[1];
    const float* qkvw = (const float*)d_in[2];
    const float* qkvb = (const float*)d_in[3];
    const float* lsc  = (const float*)d_in[4];
    const float* w1   = (const float*)d_in[5];
    const float* b1   = (const float*)d_in[6];
    const float* w2   = (const float*)d_in[7];
    const float* pw   = (const float*)d_in[8];
    const float* pb   = (const float*)d_in[9];
    const float* tab  = (const float*)d_in[10];
    const int*   rpi  = (const int*)d_in[11];

    char* ws = (char*)d_ws;
    short*  wq  = (short*)(ws + 0);          //   221,184 B
    short*  wp  = (short*)(ws + 221184);     //    73,728 B
    float*  tbl = (float*)(ws + 294912);     //    12,288 B
    __half* bm  = (__half*)(ws + 307200);    // 8,429,568 B
    float*  outp = (float*)d_out;

    k_wcvt<<<576, 256, 0, stream>>>(qkvw, pw, wq, wp);
    k_tbl<<<507, 64, 0, stream>>>(tab, w1, b1, w2, tbl);
    k_bm<<<16464, 256, 0, stream>>>(tbl, rpi, mask, bm);
    k_fused<<<2048, 448, 0, stream>>>(x, wq, qkvb, lsc, wp, pb, bm, outp);
}

// Round 5
// 377.768 us; speedup vs baseline: 1.7887x; 1.1464x over previous
//
#include <hip/hip_runtime.h>
#include <hip/hip_bf16.h>
#include <hip/hip_fp16.h>

typedef __attribute__((ext_vector_type(8))) short short8;
typedef __attribute__((ext_vector_type(4))) float f32x4;
typedef __attribute__((ext_vector_type(4))) unsigned short us4;

#define MFMA16(a, b, c) __builtin_amdgcn_mfma_f32_16x16x32_bf16(a, b, c, 0, 0, 0)
#define LN100 4.605170185988091f

__device__ __forceinline__ short f2bf(float f) {
    unsigned u = __float_as_uint(f);
    unsigned r = (u + 0x7fffu + ((u >> 16) & 1u)) >> 16;
    return (short)r;
}
__device__ __forceinline__ float h2f(unsigned short u) {
    __half_raw r; r.x = u;
    return __half2float(__half(r));
}

// ---------------- prep kernels ----------------

__global__ __launch_bounds__(256) void k_wcvt(const float* qkv_w, const float* proj_w,
                                              short* wq, short* wp) {
    int i = blockIdx.x * 256 + threadIdx.x;
    if (i < 576 * 192) wq[i] = f2bf(qkv_w[i]);
    else {
        int j = i - 576 * 192;
        if (j < 192 * 192) wp[j] = f2bf(proj_w[j]);
    }
}

// cpb MLP: 507 entries, 3 -> 512 relu -> 6
__global__ __launch_bounds__(64) void k_tbl(const float* tab, const float* w1, const float* b1,
                                            const float* w2, float* tbl) {
    int e = blockIdx.x;
    int t = threadIdx.x;
    float c0 = tab[e * 3 + 0], c1 = tab[e * 3 + 1], c2 = tab[e * 3 + 2];
    float acc[6] = {0.f, 0.f, 0.f, 0.f, 0.f, 0.f};
    for (int u = t; u < 512; u += 64) {
        float hv = c0 * w1[u * 3 + 0] + c1 * w1[u * 3 + 1] + c2 * w1[u * 3 + 2] + b1[u];
        hv = fmaxf(hv, 0.f);
        #pragma unroll
        for (int hh = 0; hh < 6; ++hh) acc[hh] += hv * w2[hh * 512 + u];
    }
    #pragma unroll
    for (int hh = 0; hh < 6; ++hh) {
        float v = acc[hh];
        for (int off = 32; off > 0; off >>= 1) v += __shfl_xor(v, off, 64);
        if (t == 0) tbl[e * 6 + hh] = v;
    }
}

// bm[w][h][q][k112] = 16*sigmoid(cpb) + mask (fp16), -60000 for k>=98
__global__ __launch_bounds__(256) void k_bm(const float* tbl, const int* rpi, const float* mask,
                                            __half* bm) {
    int i = blockIdx.x * 256 + threadIdx.x;
    if (i >= 64 * 6 * 98 * 112) return;
    int k = i % 112;
    int q = (i / 112) % 98;
    int h = (i / (112 * 98)) % 6;
    int w = i / (112 * 98 * 6);
    float v;
    if (k < 98) {
        float t = tbl[rpi[q * 98 + k] * 6 + h];
        v = 16.f / (1.f + expf(-t)) + mask[(w * 98 + q) * 98 + k];
    } else v = -60000.f;
    bm[i] = __float2half(v);
}

// ---------------- fully fused kernel: one block per window, 14 waves ----------------
// LDS (shorts): Qs[112][192]@0, Ks[112][192]@21504, VT 6x[32][128]@43008 (ao
// overlay 6x[112][32]), Bs[64][192]@67584.  XOR chunk swizzle: chunk^=(row&7).
// Wave (rg,hf): rg=wv>>1 owns rows rg*16..+16; hf=wv&1 splits cols/heads.
__global__ __launch_bounds__(896) void k_fused(const float* x, const short* wq, const float* qkv_b,
                                               const float* lsc, const short* wp, const float* proj_b,
                                               const __half* bm, float* outp) {
    __shared__ short lds[79872];
    short* Qs = lds;
    short* Ks = lds + 21504;
    short* VT = lds + 43008;
    short* Bs = lds + 67584;

    const int tid = threadIdx.x;
    const int wv = tid >> 6;
    const int lane = tid & 63;
    const int l16 = lane & 15, q4 = lane >> 4;
    const int rg = wv >> 1;
    const int hf = wv & 1;
    const int b = blockIdx.x;
    const int w = b & 63;
    const f32x4 zz = {0.f, 0.f, 0.f, 0.f};

    // zero VT (incl. token pad 98..127)
    {
        short8 z = {0, 0, 0, 0, 0, 0, 0, 0};
        #pragma unroll
        for (int it = 0; it < 4; ++it) {
            int c = tid + it * 896;
            if (c < 3072) *(short8*)&VT[c * 8] = z;
        }
    }
    // x A-frags: 16 rows per row-group, K=192, fp32->bf16 in-register
    short8 af[6];
    {
        int arow = rg * 16 + l16; if (arow > 97) arow = 97;
        const float* xp = x + ((size_t)b * 98 + arow) * 192 + q4 * 8;
        #pragma unroll
        for (int ks = 0; ks < 6; ++ks) {
            float4 f0 = *(const float4*)(xp + ks * 32);
            float4 f1 = *(const float4*)(xp + ks * 32 + 4);
            union { int i4[4]; short8 s; } u;
            asm("v_cvt_pk_bf16_f32 %0, %1, %2" : "=v"(u.i4[0]) : "v"(f0.x), "v"(f0.y));
            asm("v_cvt_pk_bf16_f32 %0, %1, %2" : "=v"(u.i4[1]) : "v"(f0.z), "v"(f0.w));
            asm("v_cvt_pk_bf16_f32 %0, %1, %2" : "=v"(u.i4[2]) : "v"(f1.x), "v"(f1.y));
            asm("v_cvt_pk_bf16_f32 %0, %1, %2" : "=v"(u.i4[3]) : "v"(f1.z), "v"(f1.w));
            af[ks] = u.s;
        }
    }
    // prologue: stage B tile 0 (1536 short8 chunks over 896 threads)
    short8 t0, t1;
    {
        int c1 = tid + 896;
        t0 = *(const short8*)(wq + (tid / 24) * 192 + (tid % 24) * 8);
        if (c1 < 1536) t1 = *(const short8*)(wq + (c1 / 24) * 192 + (c1 % 24) * 8);
    }
    __syncthreads();   // VT zeros visible before any VT write
    {
        int c1 = tid + 896;
        *(short8*)&Bs[(tid / 24) * 192 + (((tid % 24) ^ ((tid / 24) & 7)) << 3)] = t0;
        if (c1 < 1536) *(short8*)&Bs[(c1 / 24) * 192 + (((c1 % 24) ^ ((c1 / 24) & 7)) << 3)] = t1;
    }
    __syncthreads();

    const int row_w = rg * 16 + q4 * 4;
    // ---- qkv GEMM: 9 col-tiles of 64; wave does 16 rows x 32 cols (hf half) ----
    #pragma unroll 1
    for (int nt = 0; nt < 9; ++nt) {
        if (nt < 8) {   // T14: issue next tile's loads before compute
            const short* wn = wq + (nt + 1) * 64 * 192;
            int c1 = tid + 896;
            t0 = *(const short8*)(wn + (tid / 24) * 192 + (tid % 24) * 8);
            if (c1 < 1536) t1 = *(const short8*)(wn + (c1 / 24) * 192 + (c1 % 24) * 8);
        }
        f32x4 acc[2] = {zz, zz};
        #pragma unroll
        for (int ks = 0; ks < 6; ++ks)
            #pragma unroll
            for (int cf = 0; cf < 2; ++cf) {
                short8 bf = *(const short8*)&Bs[((hf * 2 + cf) * 16 + l16) * 192 +
                                                (((ks * 4 + q4) ^ (l16 & 7)) << 3)];
                acc[cf] = MFMA16(af[ks], bf, acc[cf]);
            }
        {
            int slot = nt * 2 + hf;
            int which = slot / 6;
            int h = slot - which * 6;
            float bia0 = qkv_b[slot * 32 + l16];
            float bia1 = qkv_b[slot * 32 + 16 + l16];
            float sc = 1.0f;
            if (which == 0) sc = __expf(fminf(lsc[h], LN100));
            #pragma unroll
            for (int i = 0; i < 4; ++i) {
                float v0 = acc[0][i] + bia0;
                float v1 = acc[1][i] + bia1;
                if (which < 2) {
                    float ss = v0 * v0 + v1 * v1;
                    ss += __shfl_xor(ss, 1, 16);
                    ss += __shfl_xor(ss, 2, 16);
                    ss += __shfl_xor(ss, 4, 16);
                    ss += __shfl_xor(ss, 8, 16);
                    float rn = sc / fmaxf(sqrtf(ss), 1e-12f);
                    v0 *= rn; v1 *= rn;
                }
                int row = row_w + i;
                if (which == 2) {
                    int swz = (((row >> 3) ^ (l16 & 7)) << 3) + (row & 7);
                    VT[h * 4096 + l16 * 128 + swz]        = f2bf(v0);
                    VT[h * 4096 + (l16 + 16) * 128 + swz] = f2bf(v1);
                } else {
                    short* T = (which == 0) ? Qs : Ks;
                    int c0i = h * 32 + l16, c1i = c0i + 16;
                    T[row * 192 + (((c0i >> 3) ^ (row & 7)) << 3) + (c0i & 7)] = f2bf(v0);
                    T[row * 192 + (((c1i >> 3) ^ (row & 7)) << 3) + (c1i & 7)] = f2bf(v1);
                }
            }
        }
        __syncthreads();
        if (nt < 8) {
            int c1 = tid + 896;
            *(short8*)&Bs[(tid / 24) * 192 + (((tid % 24) ^ ((tid / 24) & 7)) << 3)] = t0;
            if (c1 < 1536) *(short8*)&Bs[(c1 / 24) * 192 + (((c1 % 24) ^ ((c1 / 24) & 7)) << 3)] = t1;
            __syncthreads();
        }
    }

    // ---- attention: 3 heads per wave (hf*3 .. hf*3+2), 16 q-rows ----
    const int rq = rg * 16 + l16;
    const int qc = rq < 98 ? rq : 97;
    const int srcA = ((q4 & 1) * 2) * 16 + l16;
    const int srcB = srcA + 16;
    const bool hi = (q4 & 2) != 0;

    #pragma unroll 1
    for (int j = 0; j < 3; ++j) {
        const int h = hf * 3 + j;
        const __half* bmp = bm + (((size_t)w * 6 + h) * 98 + qc) * 112;
        us4 bh[7];
        #pragma unroll
        for (int ct = 0; ct < 7; ++ct) bh[ct] = *(const us4*)(bmp + ct * 16 + q4 * 4);
        short8 qf = *(const short8*)&Qs[rq * 192 + (((h * 4 + q4) ^ (l16 & 7)) << 3)];
        f32x4 cc[7];
        #pragma unroll
        for (int ct = 0; ct < 7; ++ct) {
            int rk = ct * 16 + l16;
            short8 kf = *(const short8*)&Ks[rk * 192 + (((h * 4 + q4) ^ (l16 & 7)) << 3)];
            cc[ct] = MFMA16(kf, qf, zz);
        }
        float mx = -1e30f;
        #pragma unroll
        for (int ct = 0; ct < 7; ++ct)
            #pragma unroll
            for (int i = 0; i < 4; ++i) {
                float s = cc[ct][i] + h2f(bh[ct][i]);
                cc[ct][i] = s;
                mx = fmaxf(mx, s);
            }
        mx = fmaxf(mx, __shfl_xor(mx, 16, 64));
        mx = fmaxf(mx, __shfl_xor(mx, 32, 64));
        float sm = 0.f;
        #pragma unroll
        for (int ct = 0; ct < 7; ++ct)
            #pragma unroll
            for (int i = 0; i < 4; ++i) {
                float e = __expf(cc[ct][i] - mx);
                cc[ct][i] = e;
                sm += e;
            }
        sm += __shfl_xor(sm, 16, 64);
        sm += __shfl_xor(sm, 32, 64);
        float ri = 1.f / sm;
        int W[8][2];
        W[7][0] = 0; W[7][1] = 0;
        #pragma unroll
        for (int ct = 0; ct < 7; ++ct) {
            float a0 = cc[ct][0] * ri, a1 = cc[ct][1] * ri;
            float a2 = cc[ct][2] * ri, a3 = cc[ct][3] * ri;
            asm("v_cvt_pk_bf16_f32 %0, %1, %2" : "=v"(W[ct][0]) : "v"(a0), "v"(a1));
            asm("v_cvt_pk_bf16_f32 %0, %1, %2" : "=v"(W[ct][1]) : "v"(a2), "v"(a3));
        }
        f32x4 o0 = zz, o1 = zz;
        #pragma unroll
        for (int km = 0; km < 4; ++km) {
            int A0 = __shfl(W[2 * km][0], srcA, 64), B0 = __shfl(W[2 * km + 1][0], srcA, 64);
            int A1 = __shfl(W[2 * km][1], srcA, 64), B1 = __shfl(W[2 * km + 1][1], srcA, 64);
            int A2 = __shfl(W[2 * km][0], srcB, 64), B2 = __shfl(W[2 * km + 1][0], srcB, 64);
            int A3 = __shfl(W[2 * km][1], srcB, 64), B3 = __shfl(W[2 * km + 1][1], srcB, 64);
            union { int i4[4]; short8 s; } ua;
            ua.i4[0] = hi ? B0 : A0;
            ua.i4[1] = hi ? B1 : A1;
            ua.i4[2] = hi ? B2 : A2;
            ua.i4[3] = hi ? B3 : A3;
            int sA = h * 4096 + l16 * 128 + (((km * 4 + q4) ^ (l16 & 7)) << 3);
            short8 bv0 = *(const short8*)&VT[sA];
            short8 bv1 = *(const short8*)&VT[sA + 2048];
            o0 = MFMA16(ua.s, bv0, o0);
            o1 = MFMA16(ua.s, bv1, o1);
        }
        __syncthreads();   // all PV_h reads of VT[h], VT[h+3-side] done before ao overlay
        #pragma unroll
        for (int i = 0; i < 4; ++i) {
            int q = row_w + i;
            VT[h * 4096 + q * 32 + l16]      = f2bf(o0[i]);
            VT[h * 4096 + q * 32 + 16 + l16] = f2bf(o1[i]);
        }
    }

    // ---- proj: stage pw into Qs/Ks region, A-frags from ao overlay ----
    {
        short8 pwst[6];
        #pragma unroll
        for (int it = 0; it < 6; ++it) {
            int c = tid + it * 896;
            if (c < 4608) pwst[it] = *(const short8*)(wp + (c / 24) * 192 + (c % 24) * 8);
        }
        #pragma unroll
        for (int it = 0; it < 6; ++it) {
            int c = tid + it * 896;
            if (c < 4608)
                *(short8*)&lds[(c / 24) * 192 + (((c % 24) ^ ((c / 24) & 7)) << 3)] = pwst[it];
        }
    }
    __syncthreads();
    {
        short8 pa[6];
        #pragma unroll
        for (int ks = 0; ks < 6; ++ks)
            pa[ks] = *(const short8*)&VT[ks * 4096 + rq * 32 + q4 * 8];
        f32x4 pacc[6] = {zz, zz, zz, zz, zz, zz};
        #pragma unroll
        for (int ks = 0; ks < 6; ++ks)
            #pragma unroll
            for (int cf = 0; cf < 6; ++cf) {
                short8 bf = *(const short8*)&lds[((hf * 6 + cf) * 16 + l16) * 192 +
                                                 (((ks * 4 + q4) ^ (l16 & 7)) << 3)];
                pacc[cf] = MFMA16(pa[ks], bf, pacc[cf]);
            }
        #pragma unroll
        for (int cf = 0; cf < 6; ++cf) {
            int cg = (hf * 6 + cf) * 16 + l16;
            float bia = proj_b[cg];
            #pragma unroll
            for (int i = 0; i < 4; ++i) {
                int q = row_w + i;
                if (q < 98)
                    outp[((size_t)b * 98 + q) * 192 + cg] = pacc[cf][i] + bia;
            }
        }
    }
}

extern "C" void kernel_launch(void* const* d_in, const int* in_sizes, int n_in,
                              void* d_out, int out_size, void* d_ws, size_t ws_size,
                              hipStream_t stream) {
    const float* x    = (const float*)d_in[0];
    const float* mask = (const float*)d_in[1];
    const float* qkvw = (const float*)d_in[2];
    const float* qkvb = (const float*)d_in[3];
    const float* lsc  = (const float*)d_in[4];
    const float* w1   = (const float*)d_in[5];
    const float* b1   = (const float*)d_in[6];
    const float* w2   = (const float*)d_in[7];
    const float* pw   = (const float*)d_in[8];
    const float* pb   = (const float*)d_in[9];
    const float* tab  = (const float*)d_in[10];
    const int*   rpi  = (const int*)d_in[11];

    char* ws = (char*)d_ws;
    short*  wq  = (short*)(ws + 0);          //   221,184 B
    short*  wp  = (short*)(ws + 221184);     //    73,728 B
    float*  tbl = (float*)(ws + 294912);     //    12,288 B
    __half* bm  = (__half*)(ws + 307200);    // 8,429,568 B
    float*  outp = (float*)d_out;

    k_wcvt<<<576, 256, 0, stream>>>(qkvw, pw, wq, wp);
    k_tbl<<<507, 64, 0, stream>>>(tab, w1, b1, w2, tbl);
    k_bm<<<16464, 256, 0, stream>>>(tbl, rpi, mask, bm);
    k_fused<<<2048, 896, 0, stream>>>(x, wq, qkvb, lsc, wp, pb, bm, outp);
}

// Round 10
// 376.566 us; speedup vs baseline: 1.7944x; 1.0032x over previous
//
#include <hip/hip_runtime.h>
#include <hip/hip_bf16.h>
#include <hip/hip_fp16.h>

typedef __attribute__((ext_vector_type(8))) short short8;
typedef __attribute__((ext_vector_type(4))) float f32x4;
typedef __attribute__((ext_vector_type(4))) unsigned short us4;

#define MFMA16(a, b, c) __builtin_amdgcn_mfma_f32_16x16x32_bf16(a, b, c, 0, 0, 0)
#define LN100 4.605170185988091f

__device__ __forceinline__ short f2bf(float f) {
    unsigned u = __float_as_uint(f);
    unsigned r = (u + 0x7fffu + ((u >> 16) & 1u)) >> 16;
    return (short)r;
}
__device__ __forceinline__ float h2f(unsigned short u) {
    __half_raw r; r.x = u;
    return __half2float(__half(r));
}

// ---------------- prep kernels ----------------

__global__ __launch_bounds__(256) void k_wcvt(const float* qkv_w, const float* proj_w,
                                              short* wq, short* wp) {
    int i = blockIdx.x * 256 + threadIdx.x;
    if (i < 576 * 192) wq[i] = f2bf(qkv_w[i]);
    else {
        int j = i - 576 * 192;
        if (j < 192 * 192) wp[j] = f2bf(proj_w[j]);
    }
}

// cpb MLP: 507 entries, 3 -> 512 relu -> 6
__global__ __launch_bounds__(64) void k_tbl(const float* tab, const float* w1, const float* b1,
                                            const float* w2, float* tbl) {
    int e = blockIdx.x;
    int t = threadIdx.x;
    float c0 = tab[e * 3 + 0], c1 = tab[e * 3 + 1], c2 = tab[e * 3 + 2];
    float acc[6] = {0.f, 0.f, 0.f, 0.f, 0.f, 0.f};
    for (int u = t; u < 512; u += 64) {
        float hv = c0 * w1[u * 3 + 0] + c1 * w1[u * 3 + 1] + c2 * w1[u * 3 + 2] + b1[u];
        hv = fmaxf(hv, 0.f);
        #pragma unroll
        for (int hh = 0; hh < 6; ++hh) acc[hh] += hv * w2[hh * 512 + u];
    }
    #pragma unroll
    for (int hh = 0; hh < 6; ++hh) {
        float v = acc[hh];
        for (int off = 32; off > 0; off >>= 1) v += __shfl_xor(v, off, 64);
        if (t == 0) tbl[e * 6 + hh] = v;
    }
}

// bm[w][h][q][k112] = 16*sigmoid(cpb) + mask (fp16), -60000 for k>=98
__global__ __launch_bounds__(256) void k_bm(const float* tbl, const int* rpi, const float* mask,
                                            __half* bm) {
    int i = blockIdx.x * 256 + threadIdx.x;
    if (i >= 64 * 6 * 98 * 112) return;
    int k = i % 112;
    int q = (i / 112) % 98;
    int h = (i / (112 * 98)) % 6;
    int w = i / (112 * 98 * 6);
    float v;
    if (k < 98) {
        float t = tbl[rpi[q * 98 + k] * 6 + h];
        v = 16.f / (1.f + expf(-t)) + mask[(w * 98 + q) * 98 + k];
    } else v = -60000.f;
    bm[i] = __float2half(v);
}

// ---------------- fully fused kernel: one block per window, 14 waves ----------------
// LDS (shorts): Qs[112][192]@0, Ks[112][192]@21504, VT 6x[32][128]@43008 (ao
// overlay 6x[112][32]), Bs[64][192]@67584.  XOR chunk swizzle: chunk^=(row&7).
// Wave (rg,hf): rg=wv>>1 owns rows rg*16..+16; hf=wv&1 splits cols/heads.
__global__ __launch_bounds__(896) void k_fused(const float* x, const short* wq, const float* qkv_b,
                                               const float* lsc, const short* wp, const float* proj_b,
                                               const __half* bm, float* outp) {
    __shared__ short lds[79872];
    short* Qs = lds;
    short* Ks = lds + 21504;
    short* VT = lds + 43008;
    short* Bs = lds + 67584;

    const int tid = threadIdx.x;
    const int wv = tid >> 6;
    const int lane = tid & 63;
    const int l16 = lane & 15, q4 = lane >> 4;
    const int rg = wv >> 1;
    const int hf = wv & 1;
    const int b = blockIdx.x;
    const int w = b & 63;
    const f32x4 zz = {0.f, 0.f, 0.f, 0.f};

    // zero VT (incl. token pad 98..127)
    {
        short8 z = {0, 0, 0, 0, 0, 0, 0, 0};
        #pragma unroll
        for (int it = 0; it < 4; ++it) {
            int c = tid + it * 896;
            if (c < 3072) *(short8*)&VT[c * 8] = z;
        }
    }
    // x A-frags: 16 rows per row-group, K=192, fp32->bf16 in-register
    short8 af[6];
    {
        int arow = rg * 16 + l16; if (arow > 97) arow = 97;
        const float* xp = x + ((size_t)b * 98 + arow) * 192 + q4 * 8;
        #pragma unroll
        for (int ks = 0; ks < 6; ++ks) {
            float4 f0 = *(const float4*)(xp + ks * 32);
            float4 f1 = *(const float4*)(xp + ks * 32 + 4);
            union { int i4[4]; short8 s; } u;
            asm("v_cvt_pk_bf16_f32 %0, %1, %2" : "=v"(u.i4[0]) : "v"(f0.x), "v"(f0.y));
            asm("v_cvt_pk_bf16_f32 %0, %1, %2" : "=v"(u.i4[1]) : "v"(f0.z), "v"(f0.w));
            asm("v_cvt_pk_bf16_f32 %0, %1, %2" : "=v"(u.i4[2]) : "v"(f1.x), "v"(f1.y));
            asm("v_cvt_pk_bf16_f32 %0, %1, %2" : "=v"(u.i4[3]) : "v"(f1.z), "v"(f1.w));
            af[ks] = u.s;
        }
    }
    // prologue: stage B tile 0 (1536 short8 chunks over 896 threads)
    short8 t0, t1;
    {
        int c1 = tid + 896;
        t0 = *(const short8*)(wq + (tid / 24) * 192 + (tid % 24) * 8);
        if (c1 < 1536) t1 = *(const short8*)(wq + (c1 / 24) * 192 + (c1 % 24) * 8);
    }
    __syncthreads();   // VT zeros visible before any VT write
    {
        int c1 = tid + 896;
        *(short8*)&Bs[(tid / 24) * 192 + (((tid % 24) ^ ((tid / 24) & 7)) << 3)] = t0;
        if (c1 < 1536) *(short8*)&Bs[(c1 / 24) * 192 + (((c1 % 24) ^ ((c1 / 24) & 7)) << 3)] = t1;
    }
    __syncthreads();

    const int row_w = rg * 16 + q4 * 4;
    // ---- qkv GEMM: 9 col-tiles of 64; wave does 16 rows x 32 cols (hf half) ----
    #pragma unroll 1
    for (int nt = 0; nt < 9; ++nt) {
        if (nt < 8) {   // T14: issue next tile's loads before compute
            const short* wn = wq + (nt + 1) * 64 * 192;
            int c1 = tid + 896;
            t0 = *(const short8*)(wn + (tid / 24) * 192 + (tid % 24) * 8);
            if (c1 < 1536) t1 = *(const short8*)(wn + (c1 / 24) * 192 + (c1 % 24) * 8);
        }
        f32x4 acc[2] = {zz, zz};
        #pragma unroll
        for (int ks = 0; ks < 6; ++ks)
            #pragma unroll
            for (int cf = 0; cf < 2; ++cf) {
                short8 bf = *(const short8*)&Bs[((hf * 2 + cf) * 16 + l16) * 192 +
                                                (((ks * 4 + q4) ^ (l16 & 7)) << 3)];
                acc[cf] = MFMA16(af[ks], bf, acc[cf]);
            }
        {
            int slot = nt * 2 + hf;
            int which = slot / 6;
            int h = slot - which * 6;
            float bia0 = qkv_b[slot * 32 + l16];
            float bia1 = qkv_b[slot * 32 + 16 + l16];
            float sc = 1.0f;
            if (which == 0) sc = __expf(fminf(lsc[h], LN100));
            #pragma unroll
            for (int i = 0; i < 4; ++i) {
                float v0 = acc[0][i] + bia0;
                float v1 = acc[1][i] + bia1;
                if (which < 2) {
                    float ss = v0 * v0 + v1 * v1;
                    ss += __shfl_xor(ss, 1, 16);
                    ss += __shfl_xor(ss, 2, 16);
                    ss += __shfl_xor(ss, 4, 16);
                    ss += __shfl_xor(ss, 8, 16);
                    float rn = sc / fmaxf(sqrtf(ss), 1e-12f);
                    v0 *= rn; v1 *= rn;
                }
                int row = row_w + i;
                if (which == 2) {
                    int swz = (((row >> 3) ^ (l16 & 7)) << 3) + (row & 7);
                    VT[h * 4096 + l16 * 128 + swz]        = f2bf(v0);
                    VT[h * 4096 + (l16 + 16) * 128 + swz] = f2bf(v1);
                } else {
                    short* T = (which == 0) ? Qs : Ks;
                    int c0i = h * 32 + l16, c1i = c0i + 16;
                    T[row * 192 + (((c0i >> 3) ^ (row & 7)) << 3) + (c0i & 7)] = f2bf(v0);
                    T[row * 192 + (((c1i >> 3) ^ (row & 7)) << 3) + (c1i & 7)] = f2bf(v1);
                }
            }
        }
        __syncthreads();
        if (nt < 8) {
            int c1 = tid + 896;
            *(short8*)&Bs[(tid / 24) * 192 + (((tid % 24) ^ ((tid / 24) & 7)) << 3)] = t0;
            if (c1 < 1536) *(short8*)&Bs[(c1 / 24) * 192 + (((c1 % 24) ^ ((c1 / 24) & 7)) << 3)] = t1;
            __syncthreads();
        }
    }

    // ---- attention: 3 heads per wave (hf*3 .. hf*3+2), 16 q-rows ----
    const int rq = rg * 16 + l16;
    const int qc = rq < 98 ? rq : 97;
    const int srcA = ((q4 & 1) * 2) * 16 + l16;
    const int srcB = srcA + 16;
    const bool hi = (q4 & 2) != 0;

    #pragma unroll 1
    for (int j = 0; j < 3; ++j) {
        const int h = hf * 3 + j;
        const __half* bmp = bm + (((size_t)w * 6 + h) * 98 + qc) * 112;
        us4 bh[7];
        #pragma unroll
        for (int ct = 0; ct < 7; ++ct) bh[ct] = *(const us4*)(bmp + ct * 16 + q4 * 4);
        short8 qf = *(const short8*)&Qs[rq * 192 + (((h * 4 + q4) ^ (l16 & 7)) << 3)];
        f32x4 cc[7];
        #pragma unroll
        for (int ct = 0; ct < 7; ++ct) {
            int rk = ct * 16 + l16;
            short8 kf = *(const short8*)&Ks[rk * 192 + (((h * 4 + q4) ^ (l16 & 7)) << 3)];
            cc[ct] = MFMA16(kf, qf, zz);
        }
        float mx = -1e30f;
        #pragma unroll
        for (int ct = 0; ct < 7; ++ct)
            #pragma unroll
            for (int i = 0; i < 4; ++i) {
                float s = cc[ct][i] + h2f(bh[ct][i]);
                cc[ct][i] = s;
                mx = fmaxf(mx, s);
            }
        mx = fmaxf(mx, __shfl_xor(mx, 16, 64));
        mx = fmaxf(mx, __shfl_xor(mx, 32, 64));
        float sm = 0.f;
        #pragma unroll
        for (int ct = 0; ct < 7; ++ct)
            #pragma unroll
            for (int i = 0; i < 4; ++i) {
                float e = __expf(cc[ct][i] - mx);
                cc[ct][i] = e;
                sm += e;
            }
        sm += __shfl_xor(sm, 16, 64);
        sm += __shfl_xor(sm, 32, 64);
        float ri = 1.f / sm;
        int W[8][2];
        W[7][0] = 0; W[7][1] = 0;
        #pragma unroll
        for (int ct = 0; ct < 7; ++ct) {
            float a0 = cc[ct][0] * ri, a1 = cc[ct][1] * ri;
            float a2 = cc[ct][2] * ri, a3 = cc[ct][3] * ri;
            asm("v_cvt_pk_bf16_f32 %0, %1, %2" : "=v"(W[ct][0]) : "v"(a0), "v"(a1));
            asm("v_cvt_pk_bf16_f32 %0, %1, %2" : "=v"(W[ct][1]) : "v"(a2), "v"(a3));
        }
        f32x4 o0 = zz, o1 = zz;
        #pragma unroll
        for (int km = 0; km < 4; ++km) {
            int A0 = __shfl(W[2 * km][0], srcA, 64), B0 = __shfl(W[2 * km + 1][0], srcA, 64);
            int A1 = __shfl(W[2 * km][1], srcA, 64), B1 = __shfl(W[2 * km + 1][1], srcA, 64);
            int A2 = __shfl(W[2 * km][0], srcB, 64), B2 = __shfl(W[2 * km + 1][0], srcB, 64);
            int A3 = __shfl(W[2 * km][1], srcB, 64), B3 = __shfl(W[2 * km + 1][1], srcB, 64);
            union { int i4[4]; short8 s; } ua;
            ua.i4[0] = hi ? B0 : A0;
            ua.i4[1] = hi ? B1 : A1;
            ua.i4[2] = hi ? B2 : A2;
            ua.i4[3] = hi ? B3 : A3;
            int sA = h * 4096 + l16 * 128 + (((km * 4 + q4) ^ (l16 & 7)) << 3);
            short8 bv0 = *(const short8*)&VT[sA];
            short8 bv1 = *(const short8*)&VT[sA + 2048];
            o0 = MFMA16(ua.s, bv0, o0);
            o1 = MFMA16(ua.s, bv1, o1);
        }
        __syncthreads();   // all PV_h reads of VT[h] done before ao overlay
        #pragma unroll
        for (int i = 0; i < 4; ++i) {
            int q = row_w + i;
            VT[h * 4096 + q * 32 + l16]      = f2bf(o0[i]);
            VT[h * 4096 + q * 32 + 16 + l16] = f2bf(o1[i]);
        }
    }

    // ---- proj: stage pw into Qs/Ks region, A-frags from ao overlay ----
    {
        short8 pwst[6];
        #pragma unroll
        for (int it = 0; it < 6; ++it) {
            int c = tid + it * 896;
            if (c < 4608) pwst[it] = *(const short8*)(wp + (c / 24) * 192 + (c % 24) * 8);
        }
        #pragma unroll
        for (int it = 0; it < 6; ++it) {
            int c = tid + it * 896;
            if (c < 4608)
                *(short8*)&lds[(c / 24) * 192 + (((c % 24) ^ ((c / 24) & 7)) << 3)] = pwst[it];
        }
    }
    __syncthreads();
    {
        short8 pa[6];
        #pragma unroll
        for (int ks = 0; ks < 6; ++ks)
            pa[ks] = *(const short8*)&VT[ks * 4096 + rq * 32 + q4 * 8];
        f32x4 pacc[6] = {zz, zz, zz, zz, zz, zz};
        #pragma unroll
        for (int ks = 0; ks < 6; ++ks)
            #pragma unroll
            for (int cf = 0; cf < 6; ++cf) {
                short8 bf = *(const short8*)&lds[((hf * 6 + cf) * 16 + l16) * 192 +
                                                 (((ks * 4 + q4) ^ (l16 & 7)) << 3)];
                pacc[cf] = MFMA16(pa[ks], bf, pacc[cf]);
            }
        #pragma unroll
        for (int cf = 0; cf < 6; ++cf) {
            int cg = (hf * 6 + cf) * 16 + l16;
            float bia = proj_b[cg];
            #pragma unroll
            for (int i = 0; i < 4; ++i) {
                int q = row_w + i;
                if (q < 98)
                    outp[((size_t)b * 98 + q) * 192 + cg] = pacc[cf][i] + bia;
            }
        }
    }
}

extern "C" void kernel_launch(void* const* d_in, const int* in_sizes, int n_in,
                              void* d_out, int out_size, void* d_ws, size_t ws_size,
                              hipStream_t stream) {
    const float* x    = (const float*)d_in[0];
    const float* mask = (const float*)d_in[1];
    const float* qkvw = (const float*)d_in[2];
    const float* qkvb = (const float*)d_in[3];
    const float* lsc  = (const float*)d_in[4];
    const float* w1   = (const float*)d_in[5];
    const float* b1   = (const float*)d_in[6];
    const float* w2   = (const float*)d_in[7];
    const float* pw   = (const float*)d_in[8];
    const float* pb   = (const float*)d_in[9];
    const float* tab  = (const float*)d_in[10];
    const int*   rpi  = (const int*)d_in[11];

    char* ws = (char*)d_ws;
    short*  wq  = (short*)(ws + 0);          //   221,184 B
    short*  wp  = (short*)(ws + 221184);     //    73,728 B
    float*  tbl = (float*)(ws + 294912);     //    12,288 B
    __half* bm  = (__half*)(ws + 307200);    // 8,429,568 B
    float*  outp = (float*)d_out;

    k_wcvt<<<576, 256, 0, stream>>>(qkvw, pw, wq, wp);
    k_tbl<<<507, 64, 0, stream>>>(tab, w1, b1, w2, tbl);
    k_bm<<<16464, 256, 0, stream>>>(tbl, rpi, mask, bm);
    k_fused<<<2048, 896, 0, stream>>>(x, wq, qkvb, lsc, wp, pb, bm, outp);
}

// Round 11
// 353.459 us; speedup vs baseline: 1.9117x; 1.0654x over previous
//
#include <hip/hip_runtime.h>
#include <hip/hip_bf16.h>
#include <hip/hip_fp16.h>

typedef __attribute__((ext_vector_type(8))) short short8;
typedef __attribute__((ext_vector_type(4))) float f32x4;

#define MFMA16(a, b, c) __builtin_amdgcn_mfma_f32_16x16x32_bf16(a, b, c, 0, 0, 0)
#define LN100 4.605170185988091f

__device__ __forceinline__ short f2bf(float f) {
    unsigned u = __float_as_uint(f);
    unsigned r = (u + 0x7fffu + ((u >> 16) & 1u)) >> 16;
    return (short)r;
}

// ---------------- prep kernels ----------------

// Writes weight images PRE-SWIZZLED into the exact LDS byte layout k_fused stages:
// qkv: per 64-col tile nt, L = r*192 + (((k>>3)^(r&7))<<3) + (k&7), r = col%64.
// proj: L = r*192 + (((k>>3)^(r&7))<<3) + (k&7), r = out-col (0..191).
__global__ __launch_bounds__(256) void k_wcvt(const float* qkv_w, const float* proj_w,
                                              short* wq_sw, short* wp_sw) {
    int i = blockIdx.x * 256 + threadIdx.x;
    if (i < 576 * 192) {
        int c = i / 192, k = i % 192;
        int nt = c >> 6, r = c & 63;
        int L = nt * 12288 + r * 192 + ((((k >> 3) ^ (r & 7)) << 3) | (k & 7));
        wq_sw[L] = f2bf(qkv_w[i]);
    } else {
        int j = i - 576 * 192;
        if (j < 192 * 192) {
            int r = j / 192, k = j % 192;
            int L = r * 192 + ((((k >> 3) ^ (r & 7)) << 3) | (k & 7));
            wp_sw[L] = f2bf(proj_w[j]);
        }
    }
}

// cpb MLP: 507 entries, 3 -> 512 relu -> 6
__global__ __launch_bounds__(64) void k_tbl(const float* tab, const float* w1, const float* b1,
                                            const float* w2, float* tbl) {
    int e = blockIdx.x;
    int t = threadIdx.x;
    float c0 = tab[e * 3 + 0], c1 = tab[e * 3 + 1], c2 = tab[e * 3 + 2];
    float acc[6] = {0.f, 0.f, 0.f, 0.f, 0.f, 0.f};
    for (int u = t; u < 512; u += 64) {
        float hv = c0 * w1[u * 3 + 0] + c1 * w1[u * 3 + 1] + c2 * w1[u * 3 + 2] + b1[u];
        hv = fmaxf(hv, 0.f);
        #pragma unroll
        for (int hh = 0; hh < 6; ++hh) acc[hh] += hv * w2[hh * 512 + u];
    }
    #pragma unroll
    for (int hh = 0; hh < 6; ++hh) {
        float v = acc[hh];
        for (int off = 32; off > 0; off >>= 1) v += __shfl_xor(v, off, 64);
        if (t == 0) tbl[e * 6 + hh] = v;
    }
}

// bm[w][h][q][k112] = 16*sigmoid(cpb) + mask (fp32), -60000 for k>=98
__global__ __launch_bounds__(256) void k_bm(const float* tbl, const int* rpi, const float* mask,
                                            float* bm) {
    int i = blockIdx.x * 256 + threadIdx.x;
    if (i >= 64 * 6 * 98 * 112) return;
    int k = i % 112;
    int q = (i / 112) % 98;
    int h = (i / (112 * 98)) % 6;
    int w = i / (112 * 98 * 6);
    float v;
    if (k < 98) {
        float t = tbl[rpi[q * 98 + k] * 6 + h];
        v = 16.f / (1.f + expf(-t)) + mask[(w * 98 + q) * 98 + k];
    } else v = -60000.f;
    bm[i] = v;
}

// ---------------- fully fused kernel: one block per window, 14 waves ----------------
// LDS (shorts): Qs[112][192]@0, Ks[112][192]@21504, VT 6x[32][128]@43008 (ao
// overlay 6x[112][32]), Bs[64][192]@67584.  XOR chunk swizzle: chunk^=(row&7).
// Wave (rg,hf): rg=wv>>1 owns rows rg*16..+16; hf=wv&1 splits cols/heads.
// Weight staging is LINEAR (images pre-swizzled by k_wcvt); read side unchanged.
__global__ __launch_bounds__(896) void k_fused(const float* x, const short* wq, const float* qkv_b,
                                               const float* lsc, const short* wp, const float* proj_b,
                                               const float* bm, float* outp) {
    __shared__ short lds[79872];
    short* Qs = lds;
    short* Ks = lds + 21504;
    short* VT = lds + 43008;
    short* Bs = lds + 67584;

    const int tid = threadIdx.x;
    const int wv = tid >> 6;
    const int lane = tid & 63;
    const int l16 = lane & 15, q4 = lane >> 4;
    const int rg = wv >> 1;
    const int hf = wv & 1;
    const int b = blockIdx.x;
    const int w = b & 63;
    const f32x4 zz = {0.f, 0.f, 0.f, 0.f};

    // zero VT (incl. token pad 98..127)
    {
        short8 z = {0, 0, 0, 0, 0, 0, 0, 0};
        #pragma unroll
        for (int it = 0; it < 4; ++it) {
            int c = tid + it * 896;
            if (c < 3072) *(short8*)&VT[c * 8] = z;
        }
    }
    // x A-frags: 16 rows per row-group, K=192, fp32->bf16 in-register
    short8 af[6];
    {
        int arow = rg * 16 + l16; if (arow > 97) arow = 97;
        const float* xp = x + ((size_t)b * 98 + arow) * 192 + q4 * 8;
        #pragma unroll
        for (int ks = 0; ks < 6; ++ks) {
            float4 f0 = *(const float4*)(xp + ks * 32);
            float4 f1 = *(const float4*)(xp + ks * 32 + 4);
            union { int i4[4]; short8 s; } u;
            asm("v_cvt_pk_bf16_f32 %0, %1, %2" : "=v"(u.i4[0]) : "v"(f0.x), "v"(f0.y));
            asm("v_cvt_pk_bf16_f32 %0, %1, %2" : "=v"(u.i4[1]) : "v"(f0.z), "v"(f0.w));
            asm("v_cvt_pk_bf16_f32 %0, %1, %2" : "=v"(u.i4[2]) : "v"(f1.x), "v"(f1.y));
            asm("v_cvt_pk_bf16_f32 %0, %1, %2" : "=v"(u.i4[3]) : "v"(f1.z), "v"(f1.w));
            af[ks] = u.s;
        }
    }
    // prologue: stage B tile 0 (1536 short8 chunks over 896 threads), LINEAR copy
    short8 t0, t1;
    {
        t0 = *(const short8*)(wq + tid * 8);
        if (tid < 640) t1 = *(const short8*)(wq + (tid + 896) * 8);
    }
    __syncthreads();   // VT zeros visible before any VT write
    {
        *(short8*)&Bs[tid * 8] = t0;
        if (tid < 640) *(short8*)&Bs[(tid + 896) * 8] = t1;
    }
    __syncthreads();

    const int row_w = rg * 16 + q4 * 4;
    // ---- qkv GEMM: 9 col-tiles of 64; wave does 16 rows x 32 cols (hf half) ----
    #pragma unroll 1
    for (int nt = 0; nt < 9; ++nt) {
        if (nt < 8) {   // T14: issue next tile's loads before compute (linear image copy)
            const short* wn = wq + (nt + 1) * 12288;
            t0 = *(const short8*)(wn + tid * 8);
            if (tid < 640) t1 = *(const short8*)(wn + (tid + 896) * 8);
        }
        f32x4 acc[2] = {zz, zz};
        #pragma unroll
        for (int ks = 0; ks < 6; ++ks)
            #pragma unroll
            for (int cf = 0; cf < 2; ++cf) {
                short8 bf = *(const short8*)&Bs[((hf * 2 + cf) * 16 + l16) * 192 +
                                                (((ks * 4 + q4) ^ (l16 & 7)) << 3)];
                acc[cf] = MFMA16(af[ks], bf, acc[cf]);
            }
        {
            int slot = nt * 2 + hf;
            int which = slot / 6;
            int h = slot - which * 6;
            float bia0 = qkv_b[slot * 32 + l16];
            float bia1 = qkv_b[slot * 32 + 16 + l16];
            float sc = 1.0f;
            if (which == 0) sc = __expf(fminf(lsc[h], LN100));
            #pragma unroll
            for (int i = 0; i < 4; ++i) {
                float v0 = acc[0][i] + bia0;
                float v1 = acc[1][i] + bia1;
                if (which < 2) {
                    float ss = v0 * v0 + v1 * v1;
                    ss += __shfl_xor(ss, 1, 16);
                    ss += __shfl_xor(ss, 2, 16);
                    ss += __shfl_xor(ss, 4, 16);
                    ss += __shfl_xor(ss, 8, 16);
                    float rn = sc / fmaxf(sqrtf(ss), 1e-12f);
                    v0 *= rn; v1 *= rn;
                }
                int row = row_w + i;
                if (which == 2) {
                    int swz = (((row >> 3) ^ (l16 & 7)) << 3) + (row & 7);
                    VT[h * 4096 + l16 * 128 + swz]        = f2bf(v0);
                    VT[h * 4096 + (l16 + 16) * 128 + swz] = f2bf(v1);
                } else {
                    short* T = (which == 0) ? Qs : Ks;
                    int c0i = h * 32 + l16, c1i = c0i + 16;
                    T[row * 192 + (((c0i >> 3) ^ (row & 7)) << 3) + (c0i & 7)] = f2bf(v0);
                    T[row * 192 + (((c1i >> 3) ^ (row & 7)) << 3) + (c1i & 7)] = f2bf(v1);
                }
            }
        }
        __syncthreads();
        if (nt < 8) {
            *(short8*)&Bs[tid * 8] = t0;
            if (tid < 640) *(short8*)&Bs[(tid + 896) * 8] = t1;
            __syncthreads();
        }
    }

    // ---- attention: 3 heads per wave (hf*3 .. hf*3+2), 16 q-rows ----
    const int rq = rg * 16 + l16;
    const int qc = rq < 98 ? rq : 97;
    const int srcA = ((q4 & 1) * 2) * 16 + l16;
    const int srcB = srcA + 16;
    const bool hi = (q4 & 2) != 0;

    #pragma unroll 1
    for (int j = 0; j < 3; ++j) {
        const int h = hf * 3 + j;
        const float* bmp = bm + (((size_t)w * 6 + h) * 98 + qc) * 112;
        f32x4 bh[7];
        #pragma unroll
        for (int ct = 0; ct < 7; ++ct) bh[ct] = *(const f32x4*)(bmp + ct * 16 + q4 * 4);
        short8 qf = *(const short8*)&Qs[rq * 192 + (((h * 4 + q4) ^ (l16 & 7)) << 3)];
        f32x4 cc[7];
        #pragma unroll
        for (int ct = 0; ct < 7; ++ct) {
            int rk = ct * 16 + l16;
            short8 kf = *(const short8*)&Ks[rk * 192 + (((h * 4 + q4) ^ (l16 & 7)) << 3)];
            cc[ct] = MFMA16(kf, qf, zz);
        }
        float mx = -1e30f;
        #pragma unroll
        for (int ct = 0; ct < 7; ++ct)
            #pragma unroll
            for (int i = 0; i < 4; ++i) {
                float s = cc[ct][i] + bh[ct][i];
                cc[ct][i] = s;
                mx = fmaxf(mx, s);
            }
        mx = fmaxf(mx, __shfl_xor(mx, 16, 64));
        mx = fmaxf(mx, __shfl_xor(mx, 32, 64));
        float sm = 0.f;
        #pragma unroll
        for (int ct = 0; ct < 7; ++ct)
            #pragma unroll
            for (int i = 0; i < 4; ++i) {
                float e = __expf(cc[ct][i] - mx);
                cc[ct][i] = e;
                sm += e;
            }
        sm += __shfl_xor(sm, 16, 64);
        sm += __shfl_xor(sm, 32, 64);
        float ri = 1.f / sm;
        int W[8][2];
        W[7][0] = 0; W[7][1] = 0;
        #pragma unroll
        for (int ct = 0; ct < 7; ++ct) {
            float a0 = cc[ct][0] * ri, a1 = cc[ct][1] * ri;
            float a2 = cc[ct][2] * ri, a3 = cc[ct][3] * ri;
            asm("v_cvt_pk_bf16_f32 %0, %1, %2" : "=v"(W[ct][0]) : "v"(a0), "v"(a1));
            asm("v_cvt_pk_bf16_f32 %0, %1, %2" : "=v"(W[ct][1]) : "v"(a2), "v"(a3));
        }
        f32x4 o0 = zz, o1 = zz;
        #pragma unroll
        for (int km = 0; km < 4; ++km) {
            int A0 = __shfl(W[2 * km][0], srcA, 64), B0 = __shfl(W[2 * km + 1][0], srcA, 64);
            int A1 = __shfl(W[2 * km][1], srcA, 64), B1 = __shfl(W[2 * km + 1][1], srcA, 64);
            int A2 = __shfl(W[2 * km][0], srcB, 64), B2 = __shfl(W[2 * km + 1][0], srcB, 64);
            int A3 = __shfl(W[2 * km][1], srcB, 64), B3 = __shfl(W[2 * km + 1][1], srcB, 64);
            union { int i4[4]; short8 s; } ua;
            ua.i4[0] = hi ? B0 : A0;
            ua.i4[1] = hi ? B1 : A1;
            ua.i4[2] = hi ? B2 : A2;
            ua.i4[3] = hi ? B3 : A3;
            int sA = h * 4096 + l16 * 128 + (((km * 4 + q4) ^ (l16 & 7)) << 3);
            short8 bv0 = *(const short8*)&VT[sA];
            short8 bv1 = *(const short8*)&VT[sA + 2048];
            o0 = MFMA16(ua.s, bv0, o0);
            o1 = MFMA16(ua.s, bv1, o1);
        }
        __syncthreads();   // all PV_h reads of VT[h] done before ao overlay
        #pragma unroll
        for (int i = 0; i < 4; ++i) {
            int q = row_w + i;
            VT[h * 4096 + q * 32 + l16]      = f2bf(o0[i]);
            VT[h * 4096 + q * 32 + 16 + l16] = f2bf(o1[i]);
        }
    }

    // ---- proj: stage pw image (linear copy) into Qs/Ks region, A-frags from ao overlay ----
    {
        short8 pwst[6];
        #pragma unroll
        for (int it = 0; it < 6; ++it) {
            int c = tid + it * 896;
            if (c < 4608) pwst[it] = *(const short8*)(wp + c * 8);
        }
        #pragma unroll
        for (int it = 0; it < 6; ++it) {
            int c = tid + it * 896;
            if (c < 4608) *(short8*)&lds[c * 8] = pwst[it];
        }
    }
    __syncthreads();
    {
        short8 pa[6];
        #pragma unroll
        for (int ks = 0; ks < 6; ++ks)
            pa[ks] = *(const short8*)&VT[ks * 4096 + rq * 32 + q4 * 8];
        f32x4 pacc[6] = {zz, zz, zz, zz, zz, zz};
        #pragma unroll
        for (int ks = 0; ks < 6; ++ks)
            #pragma unroll
            for (int cf = 0; cf < 6; ++cf) {
                short8 bf = *(const short8*)&lds[((hf * 6 + cf) * 16 + l16) * 192 +
                                                 (((ks * 4 + q4) ^ (l16 & 7)) << 3)];
                pacc[cf] = MFMA16(pa[ks], bf, pacc[cf]);
            }
        #pragma unroll
        for (int cf = 0; cf < 6; ++cf) {
            int cg = (hf * 6 + cf) * 16 + l16;
            float bia = proj_b[cg];
            #pragma unroll
            for (int i = 0; i < 4; ++i) {
                int q = row_w + i;
                if (q < 98)
                    outp[((size_t)b * 98 + q) * 192 + cg] = pacc[cf][i] + bia;
            }
        }
    }
}

extern "C" void kernel_launch(void* const* d_in, const int* in_sizes, int n_in,
                              void* d_out, int out_size, void* d_ws, size_t ws_size,
                              hipStream_t stream) {
    const float* x    = (const float*)d_in[0];
    const float* mask = (const float*)d_in[1];
    const float* qkvw = (const float*)d_in[2];
    const float* qkvb = (const float*)d_in[3];
    const float* lsc  = (const float*)d_in[4];
    const float* w1   = (const float*)d_in[5];
    const float* b1   = (const float*)d_in[6];
    const float* w2   = (const float*)d_in[7];
    const float* pw   = (const float*)d_in[8];
    const float* pb   = (const float*)d_in[9];
    const float* tab  = (const float*)d_in[10];
    const int*   rpi  = (const int*)d_in[11];

    char* ws = (char*)d_ws;
    short*  wq  = (short*)(ws + 0);          //    221,184 B (9 tile images)
    short*  wp  = (short*)(ws + 221184);     //     73,728 B (proj image)
    float*  tbl = (float*)(ws + 294912);     //     12,288 B
    float*  bm  = (float*)(ws + 307200);     // 16,859,136 B (fp32 bias+mask)
    float*  outp = (float*)d_out;

    k_wcvt<<<576, 256, 0, stream>>>(qkvw, pw, wq, wp);
    k_tbl<<<507, 64, 0, stream>>>(tab, w1, b1, w2, tbl);
    k_bm<<<16464, 256, 0, stream>>>(tbl, rpi, mask, bm);
    k_fused<<<2048, 896, 0, stream>>>(x, wq, qkvb, lsc, wp, pb, bm, outp);
}